// Round 11
// baseline (172.751 us; speedup 1.0000x reference)
//
#include <hip/hip_runtime.h>
#include <utility>

using u16 = unsigned short;
using u32 = unsigned int;

typedef float  f32x4   __attribute__((ext_vector_type(4)));
typedef float  f32x16  __attribute__((ext_vector_type(16)));
typedef __bf16 bf16x8  __attribute__((ext_vector_type(8)));

#define DI __device__ __forceinline__

// ------------------------------------------------------------------
// Monomial basis under the +8 rotation group (for 32x32x16 MFMA).
// Monomials over x[0..15]: cubic (816), quadratic (136), linear (16).
// Group action: rotation by +8q mod 16 (q=0..1).  Cubic orbits all size
// 2 (parity: 3*8=24 != 0 mod 16) -> 408 reps; quad: 8 fixed orbits
// {a,a+8} + 64 size-2 -> 72 reps (8 dup slots stay null); linear -> 8
// reps.  408+72+8 = 488 = 61 chunks * 8 exactly (no padding).
// Feature slot f = chunk*16 + q*8 + j  <->  rep r = chunk*8 + j,
// monomial = rot_{8q}(rep[r]).  Lane half q = lane>>5 holds x rotated by
// 8q at the address level, so all lanes run identical compile-time code.
// Reps are lex-ordered -> consecutive cubic reps often share the (a,b)
// prefix; prefix products are compile-time-deduped per chunk (round 8).
// ------------------------------------------------------------------
struct RepT { unsigned char a, b, c, t; };   // t: 3=cubic 2=quad 1=linear 0=null
struct Tables8 {
  RepT rep[488];        // compile-time rep list for feature templates
  RepT slotmono[976];   // per feature-slot: SORTED monomial (prep gather); t=0 if dup
  int n3, n2, n1;
};

constexpr int csort3key(int w, int x, int i) {
  int a = w, b = x, c = i, t = 0;
  if (a > b) { t = a; a = b; b = t; }
  if (b > c) { t = b; b = c; c = t; }
  if (a > b) { t = a; a = b; b = t; }
  return (a << 8) | (b << 4) | c;
}
constexpr int csort2key(int a, int b) { return a <= b ? ((a << 4) | b) : ((b << 4) | a); }

constexpr Tables8 build_tables8() {
  Tables8 T = {};
  bool used3[4096] = {};
  bool used2[256] = {};
  int nr = 0;
  // cubic multisets a<=b<=c, canonical = lex-min of {self, +8 rotation}
  for (int a = 0; a < 16; a++) for (int b = a; b < 16; b++) for (int c = b; c < 16; c++) {
    const int key  = (a << 8) | (b << 4) | c;
    const int rkey = csort3key((a + 8) & 15, (b + 8) & 15, (c + 8) & 15);
    if (rkey < key) continue;                 // partner is the canonical one
    for (int q = 0; q < 2; q++) {
      const int kk = q ? rkey : key;
      if (!used3[kk]) {
        used3[kk] = true;
        const int f = (nr >> 3) * 16 + q * 8 + (nr & 7);
        T.slotmono[f].a = (unsigned char)(kk >> 8);
        T.slotmono[f].b = (unsigned char)((kk >> 4) & 15);
        T.slotmono[f].c = (unsigned char)(kk & 15);
        T.slotmono[f].t = 3;
      }
    }
    T.rep[nr].a = (unsigned char)a; T.rep[nr].b = (unsigned char)b;
    T.rep[nr].c = (unsigned char)c; T.rep[nr].t = 3; nr++;
  }
  T.n3 = nr;
  // quadratic multisets a<=b
  for (int a = 0; a < 16; a++) for (int b = a; b < 16; b++) {
    const int key  = (a << 4) | b;
    const int rkey = csort2key((a + 8) & 15, (b + 8) & 15);
    if (rkey < key) continue;
    for (int q = 0; q < 2; q++) {
      const int kk = q ? rkey : key;
      if (!used2[kk]) {                      // fixed orbits: q=1 slot stays null
        used2[kk] = true;
        const int f = (nr >> 3) * 16 + q * 8 + (nr & 7);
        T.slotmono[f].a = (unsigned char)(kk >> 4);
        T.slotmono[f].b = (unsigned char)(kk & 15);
        T.slotmono[f].c = 0;
        T.slotmono[f].t = 2;
      }
    }
    T.rep[nr].a = (unsigned char)a; T.rep[nr].b = (unsigned char)b;
    T.rep[nr].c = 0; T.rep[nr].t = 2; nr++;
  }
  T.n2 = nr;
  // linear: reps 0..7, orbit {a, a+8}
  for (int a = 0; a < 8; a++) {
    for (int q = 0; q < 2; q++) {
      const int f = (nr >> 3) * 16 + q * 8 + (nr & 7);
      T.slotmono[f].a = (unsigned char)((a + 8 * q) & 15);
      T.slotmono[f].b = 0; T.slotmono[f].c = 0; T.slotmono[f].t = 1;
    }
    T.rep[nr].a = (unsigned char)a; T.rep[nr].b = 0; T.rep[nr].c = 0;
    T.rep[nr].t = 1; nr++;
  }
  T.n1 = nr;
  return T;
}

constexpr Tables8 TT8 = build_tables8();
static_assert(TT8.n3 == 408, "cubic rep count");
static_assert(TT8.n2 == 480, "quad rep count");
static_assert(TT8.n1 == 488, "linear rep count");   // 61 chunks * 8, exact

__device__ const Tables8 g_T8 = build_tables8();   // runtime copy for prep kernel

// dims
#define BN 5888
#define CN 128
#define EN 10
#define NCHUNK 61          // 488 reps / 8; K = 976

DI u16 f2bf(float f) { union { __bf16 h; u16 s; } u; u.h = (__bf16)f; return u.s; }
DI float bf2f(u16 v) { union { u32 u; float f; } w; w.u = ((u32)v) << 16; return w.f; }

// ------------------------------------------------------------------
// prep kernel: ONE dispatch, no memset, no atomics.  One thread per
// packed-fragment u16: gathers its monomial's <=6 distinct U-index
// permutations, sums, converts to bf16, writes coalesced.
// Fragment layout (matches main's staging copy exactly):
// uint4 idx = chunk*64 + l; lane l: path = l&31, q = l>>5; u16 j in
// [0,8): feature slot = chunk*16 + q*8 + j.  Paths 28..31 are zero.
// ------------------------------------------------------------------
#define PREP_THREADS (NCHUNK * 64 * 8)     // 31232 u16 = 61 KB

__global__ void prep_kernel(const float* __restrict__ U3, const float* __restrict__ U2,
                            const float* __restrict__ U1, u16* __restrict__ Sfrag16) {
  const int tid = blockIdx.x * 256 + threadIdx.x;
  if (tid >= PREP_THREADS) return;
  const int j = tid & 7, l = (tid >> 3) & 63, chunk = tid >> 9;
  const int path = l & 31, q = l >> 5;
  const RepT m = g_T8.slotmono[chunk * 16 + q * 8 + j];
  float v = 0.f;
  if (m.t == 3 && path < 23) {
    const int a = m.a, b = m.b, d = m.c;
    v = U3[((a * 16 + b) * 16 + d) * 23 + path];
    if (a == b && b == d) {
      // single distinct permutation
    } else if (a == b) {            // (a,a,d): +ada, +daa
      v += U3[((a * 16 + d) * 16 + a) * 23 + path]
         + U3[((d * 16 + a) * 16 + a) * 23 + path];
    } else if (b == d) {            // (a,b,b): +bab, +bba
      v += U3[((b * 16 + a) * 16 + b) * 23 + path]
         + U3[((b * 16 + b) * 16 + a) * 23 + path];
    } else {                        // all distinct: 6 perms
      v += U3[((a * 16 + d) * 16 + b) * 23 + path]
         + U3[((b * 16 + a) * 16 + d) * 23 + path]
         + U3[((b * 16 + d) * 16 + a) * 23 + path]
         + U3[((d * 16 + a) * 16 + b) * 23 + path]
         + U3[((d * 16 + b) * 16 + a) * 23 + path];
    }
  } else if (m.t == 2 && path >= 23 && path < 27) {
    const int k = path - 23, a = m.a, b = m.b;
    v = U2[(a * 16 + b) * 4 + k];
    if (a != b) v += U2[(b * 16 + a) * 4 + k];
  } else if (m.t == 1 && path == 27) {
    v = U1[m.a];
  }
  Sfrag16[tid] = f2bf(v);
}

// ------------------------------------------------------------------
// main kernel (32x32x16 MFMA).  Journal of hard-won constraints:
//  - NEVER demand occupancy beyond the VGPR budget via launch_bounds
//    min-waves (round 0: clamp to 32 VGPR -> 430 MB scratch traffic).
//  - NO sched_barrier (prior round 10: 8x regression).
//  - w-reads block-coalesced once (prior round 5: 990 MB L2 fetch).
//  - Round 2: K-splitting across waves doubles per-wave fixed costs.
//  - Round 4: global A-path -> VGPR 76 (>64 halves wave cap) = 120 us.
//  - Round 5: persistent loop + loop-invariant global A-loads -> LICM
//    spill (WRITE 218 MB).  A-path stays ds_read.
//  - Rounds 6/7: dual acc / f32x2 v_pk shapes -> spill.  THE ENVELOPE
//    IS: xr[16] + one acc[16] + SCALAR temps (+4 regs tolerated, test
//    in progress this round).
//  - Round 8: prefix-dedup neutral -> muls aren't the cost.
//  - Round 9: v_cvt_pk_bf16_f32 packing: 105 -> 99 us, WRITE 2.9 MB.
//    Issue ports ~55% idle, LDS unit 28% busy -> stall is EXPOSED
//    ds_read LATENCY (only ~36 cyc between read issue and MFMA use).
// THIS ROUND: depth-2 register pipeline on A (2 bf16x8 slots, reload
// slot C&1 for chunk C+2 right after its MFMA -> ~72+ cyc cover) and
// async staging via global_load_lds width-16.
// ------------------------------------------------------------------

// first j' <= J in chunk C with the same cubic (a,b) prefix
constexpr int pfirst3(int C, int J) {
  for (int k = 0; k < J; ++k)
    if (TT8.rep[C * 8 + k].t == 3 &&
        TT8.rep[C * 8 + k].a == TT8.rep[C * 8 + J].a &&
        TT8.rep[C * 8 + k].b == TT8.rep[C * 8 + J].b)
      return k;
  return J;
}

// feature value in f32 (prefix products deduped per chunk)
template<int C, int J>
DI float featv(float* pp, const float* xr) {
  constexpr RepT rp = TT8.rep[C * 8 + J];
  if constexpr (rp.t == 3) {
    constexpr int pf = pfirst3(C, J);
    if constexpr (pf == J) pp[J] = xr[rp.a] * xr[rp.b];  // new prefix product
    return pp[pf] * xr[rp.c];
  } else if constexpr (rp.t == 2) {
    return xr[rp.a] * xr[rp.b];
  } else if constexpr (rp.t == 1) {
    return xr[rp.a];
  } else {
    return 0.f;
  }
}

// one u32 = two bf16 (RNE, identical to scalar (__bf16) cast); src0->lo16
DI u32 cvtpk(float lo, float hi) {
  u32 r;
  asm("v_cvt_pk_bf16_f32 %0, %1, %2" : "=v"(r) : "v"(lo), "v"(hi));
  return r;
}

template<int C>
DI bf16x8 make_B(const float* xr) {
  float pp[8];                 // compile-time-indexed only -> registers (SROA)
  float f[8];
  f[0] = featv<C, 0>(pp, xr);
  f[1] = featv<C, 1>(pp, xr);
  f[2] = featv<C, 2>(pp, xr);
  f[3] = featv<C, 3>(pp, xr);
  f[4] = featv<C, 4>(pp, xr);
  f[5] = featv<C, 5>(pp, xr);
  f[6] = featv<C, 6>(pp, xr);
  f[7] = featv<C, 7>(pp, xr);
  union { u32 u[4]; bf16x8 b; } r;
  r.u[0] = cvtpk(f[0], f[1]);
  r.u[1] = cvtpk(f[2], f[3]);
  r.u[2] = cvtpk(f[4], f[5]);
  r.u[3] = cvtpk(f[6], f[7]);
  return r.b;
}

template<int C>
DI bf16x8 loadA(const uint4* sfl) {
  return *reinterpret_cast<const bf16x8*>(sfl + C * 64);
}

// depth-2 pipelined chunk: consume slot C&1, then reload it for C+2.
// Peak live = 2 A-frags (+4 VGPR over r9) -- smallest possible step
// given the r6/r7 spill cliff.
template<int C>
DI void pstep(const uint4* sfl, const float* xr, f32x16& acc,
              bf16x8& s0, bf16x8& s1) {
  const bf16x8 B = make_B<C>(xr);
  bf16x8& cur = (C & 1) ? s1 : s0;           // compile-time selection
  acc = __builtin_amdgcn_mfma_f32_32x32x16_bf16(cur, B, acc, 0, 0, 0);
  if constexpr (C + 2 < NCHUNK) cur = loadA<C + 2>(sfl);
}

template<int... Cs>
DI void run_chunks(std::integer_sequence<int, Cs...>, const uint4* sfl,
                   const float* xr, f32x16& acc) {
  bf16x8 s0 = loadA<0>(sfl);
  bf16x8 s1 = loadA<1>(sfl);
  (pstep<Cs>(sfl, xr, acc, s0, s1), ...);
}

// xr[v] = x[pair][(v + 8q) & 15] via float4-group rotation (2 groups = 8)
DI void load_xr(const float* __restrict__ x, int pair, int q, float* xr) {
  const float* base = x + pair * 16;
#pragma unroll
  for (int u = 0; u < 4; u++) {
    const int g = (u + 2 * q) & 3;
    const float4 v = *(const float4*)(base + g * 4);
    xr[u * 4 + 0] = v.x;
    xr[u * 4 + 1] = v.y;
    xr[u * 4 + 2] = v.z;
    xr[u * 4 + 3] = v.w;
  }
}

// 512-thread blocks: 8 waves = 2 nodes (4 waves x 32 pairs each).
// LDS = 61 KB sfrag (shared) + 2*8 KB wbl = 77 KB -> 2 blocks/CU.
// launch_bounds (512,4): 4 waves/EU is exactly the LDS-bound occupancy.
__global__ __launch_bounds__(512, 4) void main_kernel(
    const float* __restrict__ x, const float* __restrict__ y,
    const float* __restrict__ w3, const float* __restrict__ w2, const float* __restrict__ w1,
    const uint4* __restrict__ Sfrag, float* __restrict__ out)
{
  __shared__ uint4 sfrag[NCHUNK * 64];         // 62464 B: S in A-frag order
  __shared__ u16  wbl[2][32 * 128];            // 16384 B: WB[path][c] bf16, per node
  const int tid = threadIdx.x;
  const int node0 = blockIdx.x * 2;

  // stage S via async global->LDS (16 B/lane, wave-uniform LDS base;
  // dest = base + lane*16 matches the linear layout exactly).
  {
    const int wv = tid >> 6, ln = tid & 63;
#pragma unroll
    for (int k = 0; k < 8; k++) {
      const int base = k * 512 + wv * 64;
      if (base + ln < NCHUNK * 64) {           // wave-uniform (3904 % 64 == 0)
        __builtin_amdgcn_global_load_lds(
            (const __attribute__((address_space(1))) void*)(Sfrag + base + ln),
            (__attribute__((address_space(3))) void*)(sfrag + base),
            16, 0, 0);
      }
    }
  }

  // per-node WB = y[b] @ concat(w3,w2,w1).  256 threads/node:
  // tl = tid&255 -> p = tl>>3 (32 paths), c-16-seg = (tl&7)*16.
  // Rows 28..31: wsrc null -> zeros written (branchless epilogue).
  const int nl = tid >> 8;                     // node-local index 0/1
  const int bnode = node0 + nl;
  {
    const int tl = tid & 255;
    const int p  = tl >> 3;
    const int c0 = (tl & 7) * 16;
    float yv[EN];
#pragma unroll
    for (int e = 0; e < EN; e++) yv[e] = y[bnode * EN + e];
    float acc[16];
#pragma unroll
    for (int m = 0; m < 16; m++) acc[m] = 0.f;
    const float* wsrc = nullptr; int stride = 0;
    if (p < 23)       { wsrc = w3 + p * 128;        stride = 23 * 128; }
    else if (p < 27)  { wsrc = w2 + (p - 23) * 128; stride = 4 * 128; }
    else if (p == 27) { wsrc = w1;                  stride = 128; }
    if (wsrc) {
      for (int e = 0; e < EN; e++) {
        const float* src = wsrc + e * stride + c0;
        const float4 v0 = *(const float4*)(src);
        const float4 v1 = *(const float4*)(src + 4);
        const float4 v2 = *(const float4*)(src + 8);
        const float4 v3 = *(const float4*)(src + 12);
        acc[0]  += yv[e] * v0.x; acc[1]  += yv[e] * v0.y;
        acc[2]  += yv[e] * v0.z; acc[3]  += yv[e] * v0.w;
        acc[4]  += yv[e] * v1.x; acc[5]  += yv[e] * v1.y;
        acc[6]  += yv[e] * v1.z; acc[7]  += yv[e] * v1.w;
        acc[8]  += yv[e] * v2.x; acc[9]  += yv[e] * v2.y;
        acc[10] += yv[e] * v2.z; acc[11] += yv[e] * v2.w;
        acc[12] += yv[e] * v3.x; acc[13] += yv[e] * v3.y;
        acc[14] += yv[e] * v3.z; acc[15] += yv[e] * v3.w;
      }
    }
#pragma unroll
    for (int m = 0; m < 16; m++) wbl[nl][p * 128 + c0 + m] = f2bf(acc[m]);
  }
  __syncthreads();                             // drains vmcnt (async stage) too

  // wave handles 32 pairs; 4 waves per node, 2 nodes per block
  const int w = tid >> 6, wn = w & 3, nw = w >> 2;
  const int lane = tid & 63, col = lane & 31, q = lane >> 5;
  const int mnode = node0 + nw;
  const int pair0 = mnode * 128 + wn * 32 + col;

  float xr[16];
  load_xr(x, pair0, q, xr);

  const uint4* sfl = sfrag + lane;
  f32x16 acc = {0.f, 0.f, 0.f, 0.f, 0.f, 0.f, 0.f, 0.f,
                0.f, 0.f, 0.f, 0.f, 0.f, 0.f, 0.f, 0.f};
  run_chunks(std::make_integer_sequence<int, NCHUNK>{}, sfl, xr, acc);

  // epilogue: out[pair] = sum_p D[p][pair] * WB[p][c], reduce over the
  // two lane-halves.  D layout (32x32, m74/m101-verified):
  // col = lane&31 = pair, row = (reg&3) + 8*(reg>>2) + 4*q = path.
  // Rows 28..31 (q=1, reg 12..15) have zero D (zero A-rows) and zero
  // wbl -> branchless.
  const int cc = wn * 32 + col;              // channel = pair0 % 128
  float p0 = 0.f;
#pragma unroll
  for (int r = 0; r < 16; r++) {
    const int row = (r & 3) + 8 * (r >> 2) + 4 * q;
    p0 += acc[r] * bf2f(wbl[nw][row * 128 + cc]);
  }
  p0 += __shfl_xor(p0, 32);
  if (q == 0) out[pair0] = p0;
}

// ------------------------------------------------------------------
extern "C" void kernel_launch(void* const* d_in, const int* in_sizes, int n_in,
                              void* d_out, int out_size, void* d_ws, size_t ws_size,
                              hipStream_t stream) {
  const float* x  = (const float*)d_in[0];
  const float* y  = (const float*)d_in[1];
  const float* U3 = (const float*)d_in[2];
  const float* U2 = (const float*)d_in[3];
  const float* U1 = (const float*)d_in[4];
  const float* w3 = (const float*)d_in[5];
  const float* w2 = (const float*)d_in[6];
  const float* w1 = (const float*)d_in[7];
  u16*   Sfrag16 = (u16*)d_ws;
  float* out     = (float*)d_out;

  hipLaunchKernelGGL(prep_kernel, dim3(PREP_THREADS / 256), dim3(256), 0, stream,
                     U3, U2, U1, Sfrag16);
  hipLaunchKernelGGL(main_kernel, dim3(BN / 2), dim3(512), 0, stream,
                     x, y, w3, w2, w1, (const uint4*)d_ws, out);
}

// Round 13
// 171.831 us; speedup vs baseline: 1.0054x; 1.0054x over previous
//
#include <hip/hip_runtime.h>
#include <utility>

using u16 = unsigned short;
using u32 = unsigned int;

typedef float  f32x4   __attribute__((ext_vector_type(4)));
typedef float  f32x16  __attribute__((ext_vector_type(16)));
typedef __bf16 bf16x8  __attribute__((ext_vector_type(8)));

#define DI __device__ __forceinline__

// ------------------------------------------------------------------
// Monomial basis under the +8 rotation group (for 32x32x16 MFMA).
// Monomials over x[0..15]: cubic (816), quadratic (136), linear (16).
// Group action: rotation by +8q mod 16 (q=0..1).  Cubic orbits all size
// 2 (parity: 3*8=24 != 0 mod 16) -> 408 reps; quad: 8 fixed orbits
// {a,a+8} + 64 size-2 -> 72 reps (8 dup slots stay null); linear -> 8
// reps.  408+72+8 = 488 = 61 chunks * 8 exactly (no padding).
// Feature slot f = chunk*16 + q*8 + j  <->  rep r = chunk*8 + j,
// monomial = rot_{8q}(rep[r]).  Lane half q = lane>>5 holds x rotated by
// 8q at the address level, so all lanes run identical compile-time code.
// Reps are lex-ordered -> consecutive cubic reps often share the (a,b)
// prefix; prefix products are compile-time-deduped per chunk (round 8).
// ------------------------------------------------------------------
struct RepT { unsigned char a, b, c, t; };   // t: 3=cubic 2=quad 1=linear 0=null
struct Tables8 {
  RepT rep[488];        // compile-time rep list for feature templates
  RepT slotmono[976];   // per feature-slot: SORTED monomial (prep gather); t=0 if dup
  int n3, n2, n1;
};

constexpr int csort3key(int w, int x, int i) {
  int a = w, b = x, c = i, t = 0;
  if (a > b) { t = a; a = b; b = t; }
  if (b > c) { t = b; b = c; c = t; }
  if (a > b) { t = a; a = b; b = t; }
  return (a << 8) | (b << 4) | c;
}
constexpr int csort2key(int a, int b) { return a <= b ? ((a << 4) | b) : ((b << 4) | a); }

constexpr Tables8 build_tables8() {
  Tables8 T = {};
  bool used3[4096] = {};
  bool used2[256] = {};
  int nr = 0;
  // cubic multisets a<=b<=c, canonical = lex-min of {self, +8 rotation}
  for (int a = 0; a < 16; a++) for (int b = a; b < 16; b++) for (int c = b; c < 16; c++) {
    const int key  = (a << 8) | (b << 4) | c;
    const int rkey = csort3key((a + 8) & 15, (b + 8) & 15, (c + 8) & 15);
    if (rkey < key) continue;                 // partner is the canonical one
    for (int q = 0; q < 2; q++) {
      const int kk = q ? rkey : key;
      if (!used3[kk]) {
        used3[kk] = true;
        const int f = (nr >> 3) * 16 + q * 8 + (nr & 7);
        T.slotmono[f].a = (unsigned char)(kk >> 8);
        T.slotmono[f].b = (unsigned char)((kk >> 4) & 15);
        T.slotmono[f].c = (unsigned char)(kk & 15);
        T.slotmono[f].t = 3;
      }
    }
    T.rep[nr].a = (unsigned char)a; T.rep[nr].b = (unsigned char)b;
    T.rep[nr].c = (unsigned char)c; T.rep[nr].t = 3; nr++;
  }
  T.n3 = nr;
  // quadratic multisets a<=b
  for (int a = 0; a < 16; a++) for (int b = a; b < 16; b++) {
    const int key  = (a << 4) | b;
    const int rkey = csort2key((a + 8) & 15, (b + 8) & 15);
    if (rkey < key) continue;
    for (int q = 0; q < 2; q++) {
      const int kk = q ? rkey : key;
      if (!used2[kk]) {                      // fixed orbits: q=1 slot stays null
        used2[kk] = true;
        const int f = (nr >> 3) * 16 + q * 8 + (nr & 7);
        T.slotmono[f].a = (unsigned char)(kk >> 4);
        T.slotmono[f].b = (unsigned char)(kk & 15);
        T.slotmono[f].c = 0;
        T.slotmono[f].t = 2;
      }
    }
    T.rep[nr].a = (unsigned char)a; T.rep[nr].b = (unsigned char)b;
    T.rep[nr].c = 0; T.rep[nr].t = 2; nr++;
  }
  T.n2 = nr;
  // linear: reps 0..7, orbit {a, a+8}
  for (int a = 0; a < 8; a++) {
    for (int q = 0; q < 2; q++) {
      const int f = (nr >> 3) * 16 + q * 8 + (nr & 7);
      T.slotmono[f].a = (unsigned char)((a + 8 * q) & 15);
      T.slotmono[f].b = 0; T.slotmono[f].c = 0; T.slotmono[f].t = 1;
    }
    T.rep[nr].a = (unsigned char)a; T.rep[nr].b = 0; T.rep[nr].c = 0;
    T.rep[nr].t = 1; nr++;
  }
  T.n1 = nr;
  return T;
}

constexpr Tables8 TT8 = build_tables8();
static_assert(TT8.n3 == 408, "cubic rep count");
static_assert(TT8.n2 == 480, "quad rep count");
static_assert(TT8.n1 == 488, "linear rep count");   // 61 chunks * 8, exact

__device__ const Tables8 g_T8 = build_tables8();   // runtime copy for prep kernel

// dims
#define BN 5888
#define CN 128
#define EN 10
#define NCHUNK 61          // 488 reps / 8; K = 976

DI u16 f2bf(float f) { union { __bf16 h; u16 s; } u; u.h = (__bf16)f; return u.s; }
DI float bf2f(u16 v) { union { u32 u; float f; } w; w.u = ((u32)v) << 16; return w.f; }

// ------------------------------------------------------------------
// prep kernel: ONE dispatch, no memset, no atomics.  One thread per
// packed-fragment u16: gathers its monomial's <=6 distinct U-index
// permutations, sums, converts to bf16, writes coalesced.
// Fragment layout (matches main's staging copy exactly):
// uint4 idx = chunk*64 + l; lane l: path = l&31, q = l>>5; u16 j in
// [0,8): feature slot = chunk*16 + q*8 + j.  Paths 28..31 are zero.
// ------------------------------------------------------------------
#define PREP_THREADS (NCHUNK * 64 * 8)     // 31232 u16 = 61 KB

__global__ void prep_kernel(const float* __restrict__ U3, const float* __restrict__ U2,
                            const float* __restrict__ U1, u16* __restrict__ Sfrag16) {
  const int tid = blockIdx.x * 256 + threadIdx.x;
  if (tid >= PREP_THREADS) return;
  const int j = tid & 7, l = (tid >> 3) & 63, chunk = tid >> 9;
  const int path = l & 31, q = l >> 5;
  const RepT m = g_T8.slotmono[chunk * 16 + q * 8 + j];
  float v = 0.f;
  if (m.t == 3 && path < 23) {
    const int a = m.a, b = m.b, d = m.c;
    v = U3[((a * 16 + b) * 16 + d) * 23 + path];
    if (a == b && b == d) {
      // single distinct permutation
    } else if (a == b) {            // (a,a,d): +ada, +daa
      v += U3[((a * 16 + d) * 16 + a) * 23 + path]
         + U3[((d * 16 + a) * 16 + a) * 23 + path];
    } else if (b == d) {            // (a,b,b): +bab, +bba
      v += U3[((b * 16 + a) * 16 + b) * 23 + path]
         + U3[((b * 16 + b) * 16 + a) * 23 + path];
    } else {                        // all distinct: 6 perms
      v += U3[((a * 16 + d) * 16 + b) * 23 + path]
         + U3[((b * 16 + a) * 16 + d) * 23 + path]
         + U3[((b * 16 + d) * 16 + a) * 23 + path]
         + U3[((d * 16 + a) * 16 + b) * 23 + path]
         + U3[((d * 16 + b) * 16 + a) * 23 + path];
    }
  } else if (m.t == 2 && path >= 23 && path < 27) {
    const int k = path - 23, a = m.a, b = m.b;
    v = U2[(a * 16 + b) * 4 + k];
    if (a != b) v += U2[(b * 16 + a) * 4 + k];
  } else if (m.t == 1 && path == 27) {
    v = U1[m.a];
  }
  Sfrag16[tid] = f2bf(v);
}

// ------------------------------------------------------------------
// main kernel (32x32x16 MFMA).  Journal of hard-won constraints:
//  - NEVER demand occupancy beyond the VGPR budget via launch_bounds
//    min-waves (round 0: clamp to 32 VGPR -> 430 MB scratch traffic).
//  - NO sched_barrier (prior round 10: 8x regression).
//  - w-reads block-coalesced once (prior round 5: 990 MB L2 fetch).
//  - Round 2: K-splitting across waves doubles per-wave fixed costs.
//  - Round 4: global A-path -> VGPR 76 (>64 halves wave cap) = 120 us.
//  - Round 5: loop-invariant global loads inside a block loop -> LICM
//    hoists then spills (WRITE 218 MB).  A-path stays ds_read.
//  - Rounds 6/7: dual acc / f32x2 v_pk shapes -> spill.  THE ENVELOPE
//    IS: xr[16] + one acc[16] + SCALAR temps.
//  - Round 8: prefix-dedup neutral -> muls aren't the cost.
//  - Round 9 (THIS KERNEL): v_cvt_pk_bf16_f32 packing: 105 -> 99 us,
//    WRITE 2.9 MB (zero scratch).  Best passing state.
//  - Round 10: depth-2 A-prefetch + async staging NEUTRAL -> compiler
//    already schedules ds_reads optimally.
//  - Round 11: grid-coarsened loop (S staged once, asm memory clobber,
//    packed WB stores) -> NaN output.  LDS-DMA staging + its draining
//    barrier must stay in straight-line single-pass code; never span a
//    loop boundary with asm clobbers.  REVERTED.
// Structural floor assessment: issue work ~43 us (VALU+MFMA) + ~28 us
// LDS vs 99 us wall at 16 waves/CU; occupancy (6 attempts), latency
// hiding (2), VALU cuts (3), amortization (1) all exhausted within the
// spill envelope.  This is the banked optimum.
// ------------------------------------------------------------------

// first j' <= J in chunk C with the same cubic (a,b) prefix
constexpr int pfirst3(int C, int J) {
  for (int k = 0; k < J; ++k)
    if (TT8.rep[C * 8 + k].t == 3 &&
        TT8.rep[C * 8 + k].a == TT8.rep[C * 8 + J].a &&
        TT8.rep[C * 8 + k].b == TT8.rep[C * 8 + J].b)
      return k;
  return J;
}

// feature value in f32 (prefix products deduped per chunk)
template<int C, int J>
DI float featv(float* pp, const float* xr) {
  constexpr RepT rp = TT8.rep[C * 8 + J];
  if constexpr (rp.t == 3) {
    constexpr int pf = pfirst3(C, J);
    if constexpr (pf == J) pp[J] = xr[rp.a] * xr[rp.b];  // new prefix product
    return pp[pf] * xr[rp.c];
  } else if constexpr (rp.t == 2) {
    return xr[rp.a] * xr[rp.b];
  } else if constexpr (rp.t == 1) {
    return xr[rp.a];
  } else {
    return 0.f;
  }
}

// one u32 = two bf16 (RNE, identical to scalar (__bf16) cast); src0->lo16
DI u32 cvtpk(float lo, float hi) {
  u32 r;
  asm("v_cvt_pk_bf16_f32 %0, %1, %2" : "=v"(r) : "v"(lo), "v"(hi));
  return r;
}

template<int C>
DI bf16x8 make_B(const float* xr) {
  float pp[8];                 // compile-time-indexed only -> registers (SROA)
  float f[8];
  f[0] = featv<C, 0>(pp, xr);
  f[1] = featv<C, 1>(pp, xr);
  f[2] = featv<C, 2>(pp, xr);
  f[3] = featv<C, 3>(pp, xr);
  f[4] = featv<C, 4>(pp, xr);
  f[5] = featv<C, 5>(pp, xr);
  f[6] = featv<C, 6>(pp, xr);
  f[7] = featv<C, 7>(pp, xr);
  union { u32 u[4]; bf16x8 b; } r;
  r.u[0] = cvtpk(f[0], f[1]);
  r.u[1] = cvtpk(f[2], f[3]);
  r.u[2] = cvtpk(f[4], f[5]);
  r.u[3] = cvtpk(f[6], f[7]);
  return r.b;
}

// A: 32 paths x 16 K fragment from LDS (one ds_read_b128); B: 8
// features of this pair.  B built before the A-load to keep A's live
// range ds_read -> MFMA.
template<int C>
DI void chunk_step(const uint4* sfl, const float* xr, f32x16& acc) {
  const bf16x8 B = make_B<C>(xr);
  const bf16x8 A = *reinterpret_cast<const bf16x8*>(sfl + C * 64);
  acc = __builtin_amdgcn_mfma_f32_32x32x16_bf16(A, B, acc, 0, 0, 0);
}

template<int... Cs>
DI void run_chunks(std::integer_sequence<int, Cs...>, const uint4* sfl,
                   const float* xr, f32x16& acc) {
  (chunk_step<Cs>(sfl, xr, acc), ...);
}

// xr[v] = x[pair][(v + 8q) & 15] via float4-group rotation (2 groups = 8)
DI void load_xr(const float* __restrict__ x, int pair, int q, float* xr) {
  const float* base = x + pair * 16;
#pragma unroll
  for (int u = 0; u < 4; u++) {
    const int g = (u + 2 * q) & 3;
    const float4 v = *(const float4*)(base + g * 4);
    xr[u * 4 + 0] = v.x;
    xr[u * 4 + 1] = v.y;
    xr[u * 4 + 2] = v.z;
    xr[u * 4 + 3] = v.w;
  }
}

// 512-thread blocks: 8 waves = 2 nodes (4 waves x 32 pairs each).
// LDS = 61 KB sfrag (shared) + 2*8 KB wbl = 77 KB -> 2 blocks/CU.
// launch_bounds (512,4): 4 waves/EU is exactly the LDS-bound occupancy;
// proven spill-free at VGPR 64 + 16 AGPR.
__global__ __launch_bounds__(512, 4) void main_kernel(
    const float* __restrict__ x, const float* __restrict__ y,
    const float* __restrict__ w3, const float* __restrict__ w2, const float* __restrict__ w1,
    const uint4* __restrict__ Sfrag, float* __restrict__ out)
{
  __shared__ uint4 sfrag[NCHUNK * 64];         // 62464 B: S in A-frag order
  __shared__ u16  wbl[2][32 * 128];            // 16384 B: WB[path][c] bf16, per node
  const int tid = threadIdx.x;
  const int node0 = blockIdx.x * 2;

  // stage S: straight uint4 copy (prep already packed bf16 fragments)
  for (int idx = tid; idx < NCHUNK * 64; idx += 512) sfrag[idx] = Sfrag[idx];

  // per-node WB = y[b] @ concat(w3,w2,w1).  256 threads/node:
  // tl = tid&255 -> p = tl>>3 (32 paths), c-16-seg = (tl&7)*16.
  // Rows 28..31: wsrc null -> zeros written (branchless epilogue).
  const int nl = tid >> 8;                     // node-local index 0/1
  const int bnode = node0 + nl;
  {
    const int tl = tid & 255;
    const int p  = tl >> 3;
    const int c0 = (tl & 7) * 16;
    float yv[EN];
#pragma unroll
    for (int e = 0; e < EN; e++) yv[e] = y[bnode * EN + e];
    float acc[16];
#pragma unroll
    for (int m = 0; m < 16; m++) acc[m] = 0.f;
    const float* wsrc = nullptr; int stride = 0;
    if (p < 23)       { wsrc = w3 + p * 128;        stride = 23 * 128; }
    else if (p < 27)  { wsrc = w2 + (p - 23) * 128; stride = 4 * 128; }
    else if (p == 27) { wsrc = w1;                  stride = 128; }
    if (wsrc) {
      for (int e = 0; e < EN; e++) {
        const float* src = wsrc + e * stride + c0;
        const float4 v0 = *(const float4*)(src);
        const float4 v1 = *(const float4*)(src + 4);
        const float4 v2 = *(const float4*)(src + 8);
        const float4 v3 = *(const float4*)(src + 12);
        acc[0]  += yv[e] * v0.x; acc[1]  += yv[e] * v0.y;
        acc[2]  += yv[e] * v0.z; acc[3]  += yv[e] * v0.w;
        acc[4]  += yv[e] * v1.x; acc[5]  += yv[e] * v1.y;
        acc[6]  += yv[e] * v1.z; acc[7]  += yv[e] * v1.w;
        acc[8]  += yv[e] * v2.x; acc[9]  += yv[e] * v2.y;
        acc[10] += yv[e] * v2.z; acc[11] += yv[e] * v2.w;
        acc[12] += yv[e] * v3.x; acc[13] += yv[e] * v3.y;
        acc[14] += yv[e] * v3.z; acc[15] += yv[e] * v3.w;
      }
    }
#pragma unroll
    for (int m = 0; m < 16; m++) wbl[nl][p * 128 + c0 + m] = f2bf(acc[m]);
  }
  __syncthreads();

  // wave handles 32 pairs; 4 waves per node, 2 nodes per block
  const int w = tid >> 6, wn = w & 3, nw = w >> 2;
  const int lane = tid & 63, col = lane & 31, q = lane >> 5;
  const int mnode = node0 + nw;
  const int pair0 = mnode * 128 + wn * 32 + col;

  float xr[16];
  load_xr(x, pair0, q, xr);

  const uint4* sfl = sfrag + lane;
  f32x16 acc = {0.f, 0.f, 0.f, 0.f, 0.f, 0.f, 0.f, 0.f,
                0.f, 0.f, 0.f, 0.f, 0.f, 0.f, 0.f, 0.f};
  run_chunks(std::make_integer_sequence<int, NCHUNK>{}, sfl, xr, acc);

  // epilogue: out[pair] = sum_p D[p][pair] * WB[p][c], reduce over the
  // two lane-halves.  D layout (32x32, m74/m101-verified):
  // col = lane&31 = pair, row = (reg&3) + 8*(reg>>2) + 4*q = path.
  // Rows 28..31 (q=1, reg 12..15) have zero D (zero A-rows) and zero
  // wbl -> branchless.
  const int cc = wn * 32 + col;              // channel = pair0 % 128
  float p0 = 0.f;
#pragma unroll
  for (int r = 0; r < 16; r++) {
    const int row = (r & 3) + 8 * (r >> 2) + 4 * q;
    p0 += acc[r] * bf2f(wbl[nw][row * 128 + cc]);
  }
  p0 += __shfl_xor(p0, 32);
  if (q == 0) out[pair0] = p0;
}

// ------------------------------------------------------------------
extern "C" void kernel_launch(void* const* d_in, const int* in_sizes, int n_in,
                              void* d_out, int out_size, void* d_ws, size_t ws_size,
                              hipStream_t stream) {
  const float* x  = (const float*)d_in[0];
  const float* y  = (const float*)d_in[1];
  const float* U3 = (const float*)d_in[2];
  const float* U2 = (const float*)d_in[3];
  const float* U1 = (const float*)d_in[4];
  const float* w3 = (const float*)d_in[5];
  const float* w2 = (const float*)d_in[6];
  const float* w1 = (const float*)d_in[7];
  u16*   Sfrag16 = (u16*)d_ws;
  float* out     = (float*)d_out;

  hipLaunchKernelGGL(prep_kernel, dim3(PREP_THREADS / 256), dim3(256), 0, stream,
                     U3, U2, U1, Sfrag16);
  hipLaunchKernelGGL(main_kernel, dim3(BN / 2), dim3(512), 0, stream,
                     x, y, w3, w2, w1, (const uint4*)d_ws, out);
}